// Round 1
// 127.082 us; speedup vs baseline: 1.0155x; 1.0155x over previous
//
#include <hip/hip_runtime.h>

#define BIGF 1e9f
#define TT 512
#define DD 256
#define NB 64
#define DROWS 1088    // diag rows per batch (1023 used + prefetch overrun pad)
#define SAK 40        // LDS row stride in bf16 (32 data + 8 pad)
#define CST 66        // C-tile LDS stride in floats (66 -> anti-diag reads hit banks +1 apart)

typedef float floatx16 __attribute__((ext_vector_type(16)));
typedef __bf16 bf16x8 __attribute__((ext_vector_type(8)));

// ---------- DPP wave shifts: lane i <- lane i-1 (shr) / lane i+1 (shl); invalid lanes get `oldv`
__device__ __forceinline__ float dpp_wave_shr1(float x, float oldv) {
  int r = __builtin_amdgcn_update_dpp(__builtin_bit_cast(int, oldv),
                                      __builtin_bit_cast(int, x),
                                      0x138, 0xF, 0xF, false);  // WAVE_SHR1
  return __builtin_bit_cast(float, r);
}
__device__ __forceinline__ float dpp_wave_shl1(float x, float oldv) {
  int r = __builtin_amdgcn_update_dpp(__builtin_bit_cast(int, oldv),
                                      __builtin_bit_cast(int, x),
                                      0x130, 0xF, 0xF, false);  // WAVE_SHL1
  return __builtin_bit_cast(float, r);
}

// ---------- Kernel B: banded cost via bf16 MFMA + fused norms, written in diag layout ----------
// 64x64 (i,j) tile per block; 4 waves in 2x2; each wave one 32x32 MFMA accumulator.
// Grid is 1D, decoded so all 24 tiles of batch b share XCD b%8 (block n -> XCD n%8 heuristic):
// x1/x2 of a batch stay L2-resident -> fetch ~= compulsory 67 MB.
// m==0 blocks additionally paint their batch's corner-invalid diag cells with BIG.
// EPILOGUE (new): instead of 16 scattered 4B stores/thread (lane stride ~256B -> ~64 cache
// lines per wave-store), the scaled C tile is staged in LDS [64][CST] and re-read in
// diag-major order so each wave-store writes 64 CONSECUTIVE floats of one diag row.
// LDS C-buffer aliases the (dead-after-loop) sA/sB staging space.
__global__ __launch_bounds__(256) void cost_kernel(const float* __restrict__ x1,
                                                   const float* __restrict__ x2,
                                                   float* __restrict__ diag) {
  const int n = blockIdx.x;
  const int b = n & 63;       // batch; b%8 == n%8 -> XCD
  const int m = n >> 6;       // 0..23
  const int it = m & 7;       // i-tile
  const int jt = m >> 3;      // j-tile 0..2
  const int i0 = it * 64;
  const int j0 = i0 - 50 + jt * 64;

  // 64*CST floats = 16896 B; first 10240 B double as sA/sB bf16 staging during the K-loop
  __shared__ __align__(16) float sC[64 * CST];
  __bf16* sA = (__bf16*)sC;
  __bf16* sB = ((__bf16*)sC) + 64 * SAK;
  __shared__ float rA[64];  // 1/max(||x1_i||, eps) per tile row
  __shared__ float rB[64];

  const int t = threadIdx.x;
  const int lane = t & 63;
  const int w = t >> 6;       // wave 0..3
  const int wi = w >> 1;      // i-subtile (0/1)
  const int wj = w & 1;       // j-subtile (0/1)
  const int ln = lane & 31;
  const int kh = lane >> 5;   // k-half (0/1)

  float* db = diag + (size_t)b * (DROWS * 64);

  // corner paint (one block per batch; overlapped with the other 1472 blocks' compute)
  if (m == 0) {
    for (int r = w; r < 180; r += 4) {
      const int d = (r < 64) ? r : r + 908;  // [0,64) U [972,1088)
      const int p = d & 1;
      const int i = (d >> 1) + lane + p - 25;
      const int j = d - i;
      const int k = 2 * lane + p;
      if (k > 100 || (unsigned)i >= TT || (unsigned)j >= TT)
        db[(size_t)d * 64 + lane] = BIGF;
    }
  }

  // staging mapping: thread t loads row (t>>2), 8 floats at quarter (t&3)
  const int sr = t >> 2;
  const int sq = t & 3;
  const float* x1b = x1 + (size_t)b * (TT * DD);
  const float* x2b = x2 + (size_t)b * (TT * DD);
  int gj = j0 + sr;
  gj = gj < 0 ? 0 : (gj > TT - 1 ? TT - 1 : gj);
  const float* pAg = x1b + (size_t)(i0 + sr) * DD + sq * 8;
  const float* pBg = x2b + (size_t)gj * DD + sq * 8;
  __bf16* dA = sA + sr * SAK + sq * 8;
  __bf16* dB = sB + sr * SAK + sq * 8;

  const __bf16* fAp = sA + (wi * 32 + ln) * SAK + kh * 8;
  const __bf16* fBp = sB + (wj * 32 + ln) * SAK + kh * 8;

  floatx16 acc = {};
  float pa = 0.f, pb = 0.f;  // sum-of-squares partials (fp32, from original data)

  for (int kc = 0; kc < DD; kc += 32) {
    const float4 a0 = *(const float4*)(pAg + kc);
    const float4 a1 = *(const float4*)(pAg + kc + 4);
    const float4 b0 = *(const float4*)(pBg + kc);
    const float4 b1 = *(const float4*)(pBg + kc + 4);
    pa += a0.x * a0.x + a0.y * a0.y + a0.z * a0.z + a0.w * a0.w;
    pa += a1.x * a1.x + a1.y * a1.y + a1.z * a1.z + a1.w * a1.w;
    pb += b0.x * b0.x + b0.y * b0.y + b0.z * b0.z + b0.w * b0.w;
    pb += b1.x * b1.x + b1.y * b1.y + b1.z * b1.z + b1.w * b1.w;
    __syncthreads();
    {
      bf16x8 va, vb;
      va[0] = (__bf16)a0.x; va[1] = (__bf16)a0.y; va[2] = (__bf16)a0.z; va[3] = (__bf16)a0.w;
      va[4] = (__bf16)a1.x; va[5] = (__bf16)a1.y; va[6] = (__bf16)a1.z; va[7] = (__bf16)a1.w;
      vb[0] = (__bf16)b0.x; vb[1] = (__bf16)b0.y; vb[2] = (__bf16)b0.z; vb[3] = (__bf16)b0.w;
      vb[4] = (__bf16)b1.x; vb[5] = (__bf16)b1.y; vb[6] = (__bf16)b1.z; vb[7] = (__bf16)b1.w;
      *(bf16x8*)dA = va;
      *(bf16x8*)dB = vb;
    }
    __syncthreads();
    const bf16x8 fa0 = *(const bf16x8*)fAp;
    const bf16x8 fb0 = *(const bf16x8*)fBp;
    const bf16x8 fa1 = *(const bf16x8*)(fAp + 16);
    const bf16x8 fb1 = *(const bf16x8*)(fBp + 16);
    acc = __builtin_amdgcn_mfma_f32_32x32x16_bf16(fa0, fb0, acc, 0, 0, 0);
    acc = __builtin_amdgcn_mfma_f32_32x32x16_bf16(fa1, fb1, acc, 0, 0, 0);
  }

  // reduce sumsq across the 4 staging threads of each row (lanes t^1, t^2 share sr)
  pa += __shfl_xor(pa, 1, 64); pa += __shfl_xor(pa, 2, 64);
  pb += __shfl_xor(pb, 1, 64); pb += __shfl_xor(pb, 2, 64);
  if (sq == 0) {
    rA[sr] = 1.0f / fmaxf(sqrtf(pa), 1e-8f);
    rB[sr] = 1.0f / fmaxf(sqrtf(pb), 1e-8f);
  }
  __syncthreads();  // rA/rB ready; all waves past their last sA/sB reads -> safe to reuse as sC

  // scale and stage C tile in LDS: C layout col=lane&31 (rj), row=(reg&3)+8*(reg>>2)+4*kh (ri)
  // write pattern: lanes 0-31 consecutive addrs; lanes 32-63 at +4*CST=264 words (bank +8) ->
  // 2 lanes/bank = free.
  {
    const int rj = wj * 32 + ln;
    const float r2 = rB[rj];
#pragma unroll
    for (int reg = 0; reg < 16; ++reg) {
      const int ri = wi * 32 + (reg & 3) + 8 * (reg >> 2) + 4 * kh;
      sC[ri * CST + rj] = 1.0f - acc[reg] * rA[ri] * r2;
    }
  }
  __syncthreads();

  // diag-major coalesced stores: wave w handles rows r = w, w+4, ..., w+124 (d = d0 + r).
  // lane l holds band cell k = 2l + (d&1): i = l + (d + (d&1) - 50)/2, ri = i - i0, rj = r - ri.
  // LDS addr = ri*CST + rj = 65*l + (65*roff + r): lane-stride 65 (odd) -> conflict-free
  // (l and l+32 differ by 65*32 ≡ 0 mod 32 -> 2-way broadcast-free pair, free per m136).
  // global addr = db[d*64 + l]: 64 consecutive floats per wave-store -> 4 cache lines.
  {
    const int d0 = i0 + j0;
    const int a65 = 65 * lane;
#pragma unroll 4
    for (int rr = 0; rr < 32; ++rr) {
      const int r = 4 * rr + w;              // 0..127
      const int d = d0 + r;                  // may be <0 or >1022 at corner tiles: fully masked
      const int p = d & 1;
      const int roff = ((d + p - 50) >> 1) - i0;   // ri at lane 0 (d+p-50 is even)
      const int ri = lane + roff;
      const int rj = r - ri;
      const int kband = 2 * lane + p;
      const int jg = j0 + rj;
      if (((unsigned)ri < 64u) & ((unsigned)rj < 64u) & (kband <= 100) &
          ((unsigned)jg < (unsigned)TT)) {
        db[(size_t)d * 64 + lane] = sC[a65 + 65 * roff + r];
      }
    }
  }
}

// ---------- Kernel C: anti-diagonal DP, one wave per batch, coalesced diag reads ----------
// Band offset k = i-j+50; lane l holds cell k = 2l+p (p = d&1).
// new[k] = c + min(prev1[k-1], prev1[k+1], prev2[k])
//   p=1 (odd d): k-1 -> same lane, k+1 -> wave_shl1;  p=0: k-1 -> wave_shr1, k+1 -> same lane.
// Lanes l>=51 (and l==50 on odd d) are permanently out of band: their cost is forced
// to BIG via a loop-invariant cndmask on the prefetched value (off the critical chain);
// corner diagonals were BIG-painted by cost_kernel's m==0 blocks.
__global__ __launch_bounds__(64) void dtw_dp_kernel(const float* __restrict__ diag,
                                                    float* __restrict__ out) {
  const int b = blockIdx.x;
  const int l = threadIdx.x;
  const bool inv_odd = (l >= 50);   // k=2l+1 > 100
  const bool inv_even = (l >= 51);  // k=2l   > 100
  const float* base = diag + (size_t)b * (DROWS * 64);
  const float* pO = base + 64 + l;   // d = 1
  const float* pE = base + 128 + l;  // d = 2
  float cr[32];
#pragma unroll
  for (int t = 0; t < 16; ++t) {
    cr[2 * t] = *pO; pO += 128;
    cr[2 * t + 1] = *pE; pE += 128;
  }
  float prev2 = BIGF;
  const float c00 = base[25];          // cost(0,0) lives at d=0, lane 25
  float prev1 = (l == 25) ? c00 : BIGF;
  float ans = BIGF;
  for (int it = 0; it < 32; ++it) {
#pragma unroll
    for (int u = 0; u < 16; ++u) {
      // odd diagonal
      const float c1 = inv_odd ? BIGF : cr[2 * u];
      cr[2 * u] = *pO; pO += 128;  // prefetch 32 diagonals ahead (stays within DROWS pad)
      const float sh = dpp_wave_shl1(prev1, BIGF);
      const float m3 = fminf(fminf(prev1, sh), prev2);
      prev2 = prev1;
      prev1 = c1 + m3;
      // even diagonal
      const float c2 = inv_even ? BIGF : cr[2 * u + 1];
      cr[2 * u + 1] = *pE; pE += 128;
      const float sh2 = dpp_wave_shr1(prev1, BIGF);
      const float m32 = fminf(fminf(sh2, prev1), prev2);
      prev2 = prev1;
      prev1 = c2 + m32;
      if (u == 14 && it == 31) ans = prev1;  // d = 1022 -> cell (511,511) at lane 25
    }
  }
  if (l == 25) out[b] = ans;
}

extern "C" void kernel_launch(void* const* d_in, const int* in_sizes, int n_in,
                              void* d_out, int out_size, void* d_ws, size_t ws_size,
                              hipStream_t stream) {
  const float* x1 = (const float*)d_in[0];
  const float* x2 = (const float*)d_in[1];
  float* out = (float*)d_out;
  float* diag = (float*)d_ws;  // 64*1088*64 floats = 17.8 MB

  cost_kernel<<<NB * 24, 256, 0, stream>>>(x1, x2, diag);
  dtw_dp_kernel<<<NB, 64, 0, stream>>>(diag, out);
}

// Round 2
// 126.590 us; speedup vs baseline: 1.0195x; 1.0039x over previous
//
#include <hip/hip_runtime.h>

#define BIGF 1e9f
#define TT 512
#define DD 256
#define NB 64
#define DROWS 1088    // diag rows per batch (1023 used + prefetch overrun pad)
#define SAK 40        // LDS row stride in bf16 (32 data + 8 pad)
#define CST 66        // C-tile LDS stride in floats (66 -> anti-diag reads hit banks +1 apart)

typedef float floatx16 __attribute__((ext_vector_type(16)));
typedef __bf16 bf16x8 __attribute__((ext_vector_type(8)));

// ---------- DPP wave shifts: lane i <- lane i-1 (shr) / lane i+1 (shl); invalid lanes get `oldv`
__device__ __forceinline__ float dpp_wave_shr1(float x, float oldv) {
  int r = __builtin_amdgcn_update_dpp(__builtin_bit_cast(int, oldv),
                                      __builtin_bit_cast(int, x),
                                      0x138, 0xF, 0xF, false);  // WAVE_SHR1
  return __builtin_bit_cast(float, r);
}
__device__ __forceinline__ float dpp_wave_shl1(float x, float oldv) {
  int r = __builtin_amdgcn_update_dpp(__builtin_bit_cast(int, oldv),
                                      __builtin_bit_cast(int, x),
                                      0x130, 0xF, 0xF, false);  // WAVE_SHL1
  return __builtin_bit_cast(float, r);
}

// ---------- Kernel B: banded cost via bf16 MFMA + fused norms, written in diag layout ----------
// PERSISTENT-BLOCK VERSION: 768 blocks (3/CU), each processes 2 tiles.
// Per XCD x (block p -> XCD p%8 heuristic): 96 blocks cover the 192 tiles of the 8 batches
// with b%8==x, enumerated BATCH-MAJOR (T = pl + 96*kt, bhi = T/24). At any instant an XCD's
// blocks span ~96 consecutive T = ~4 batches = ~4 MB fp32 -> fits the 4 MB per-XCD L2,
// vs the old all-64-batches-concurrent layout (8 MB/XCD -> thrash, ~3x compulsory fetch).
// m==0 tiles additionally paint their batch's corner-invalid diag cells with BIG.
__global__ __launch_bounds__(256) void cost_kernel(const float* __restrict__ x1,
                                                   const float* __restrict__ x2,
                                                   float* __restrict__ diag) {
  const int p = blockIdx.x;   // 0..767
  const int x = p & 7;        // XCD
  const int pl = p >> 3;      // 0..95 within XCD

  // 64*CST floats = 16896 B; first 10240 B double as sA/sB bf16 staging during the K-loop
  __shared__ __align__(16) float sC[64 * CST];
  __bf16* sA = (__bf16*)sC;
  __bf16* sB = ((__bf16*)sC) + 64 * SAK;
  __shared__ float rA[64];  // 1/max(||x1_i||, eps) per tile row
  __shared__ float rB[64];

  const int t = threadIdx.x;
  const int lane = t & 63;
  const int w = t >> 6;       // wave 0..3
  const int wi = w >> 1;      // i-subtile (0/1)
  const int wj = w & 1;       // j-subtile (0/1)
  const int ln = lane & 31;
  const int kh = lane >> 5;   // k-half (0/1)

  // thread-static staging/fragment addresses (tile-independent)
  const int sr = t >> 2;      // staging row
  const int sq = t & 3;       // staging quarter
  __bf16* dA = sA + sr * SAK + sq * 8;
  __bf16* dB = sB + sr * SAK + sq * 8;
  const __bf16* fAp = sA + (wi * 32 + ln) * SAK + kh * 8;
  const __bf16* fBp = sB + (wj * 32 + ln) * SAK + kh * 8;

  for (int kt = 0; kt < 2; ++kt) {
    const int T = pl + 96 * kt;     // 0..191, batch-major within XCD
    const int bhi = T / 24;         // 0..7
    const int m = T - bhi * 24;     // 0..23
    const int b = bhi * 8 + x;      // batch, b%8 == XCD
    const int it = m & 7;           // i-tile
    const int jt = m >> 3;          // j-tile 0..2
    const int i0 = it * 64;
    const int j0 = i0 - 50 + jt * 64;

    float* db = diag + (size_t)b * (DROWS * 64);

    // corner paint (one tile per batch; disjoint from all valid-cell writes -> no sync)
    if (m == 0) {
      for (int r = w; r < 180; r += 4) {
        const int d = (r < 64) ? r : r + 908;  // [0,64) U [972,1088)
        const int pp = d & 1;
        const int i = (d >> 1) + lane + pp - 25;
        const int j = d - i;
        const int k = 2 * lane + pp;
        if (k > 100 || (unsigned)i >= TT || (unsigned)j >= TT)
          db[(size_t)d * 64 + lane] = BIGF;
      }
    }

    const float* x1b = x1 + (size_t)b * (TT * DD);
    const float* x2b = x2 + (size_t)b * (TT * DD);
    int gj = j0 + sr;
    gj = gj < 0 ? 0 : (gj > TT - 1 ? TT - 1 : gj);
    const float* pAg = x1b + (size_t)(i0 + sr) * DD + sq * 8;
    const float* pBg = x2b + (size_t)gj * DD + sq * 8;

    floatx16 acc = {};
    float pa = 0.f, pb = 0.f;  // sum-of-squares partials (fp32, from original data)

    for (int kc = 0; kc < DD; kc += 32) {
      const float4 a0 = *(const float4*)(pAg + kc);
      const float4 a1 = *(const float4*)(pAg + kc + 4);
      const float4 b0 = *(const float4*)(pBg + kc);
      const float4 b1 = *(const float4*)(pBg + kc + 4);
      pa += a0.x * a0.x + a0.y * a0.y + a0.z * a0.z + a0.w * a0.w;
      pa += a1.x * a1.x + a1.y * a1.y + a1.z * a1.z + a1.w * a1.w;
      pb += b0.x * b0.x + b0.y * b0.y + b0.z * b0.z + b0.w * b0.w;
      pb += b1.x * b1.x + b1.y * b1.y + b1.z * b1.z + b1.w * b1.w;
      // barrier also fences the previous tile's sC reads before we overwrite sA/sB (alias)
      __syncthreads();
      {
        bf16x8 va, vb;
        va[0] = (__bf16)a0.x; va[1] = (__bf16)a0.y; va[2] = (__bf16)a0.z; va[3] = (__bf16)a0.w;
        va[4] = (__bf16)a1.x; va[5] = (__bf16)a1.y; va[6] = (__bf16)a1.z; va[7] = (__bf16)a1.w;
        vb[0] = (__bf16)b0.x; vb[1] = (__bf16)b0.y; vb[2] = (__bf16)b0.z; vb[3] = (__bf16)b0.w;
        vb[4] = (__bf16)b1.x; vb[5] = (__bf16)b1.y; vb[6] = (__bf16)b1.z; vb[7] = (__bf16)b1.w;
        *(bf16x8*)dA = va;
        *(bf16x8*)dB = vb;
      }
      __syncthreads();
      const bf16x8 fa0 = *(const bf16x8*)fAp;
      const bf16x8 fb0 = *(const bf16x8*)fBp;
      const bf16x8 fa1 = *(const bf16x8*)(fAp + 16);
      const bf16x8 fb1 = *(const bf16x8*)(fBp + 16);
      acc = __builtin_amdgcn_mfma_f32_32x32x16_bf16(fa0, fb0, acc, 0, 0, 0);
      acc = __builtin_amdgcn_mfma_f32_32x32x16_bf16(fa1, fb1, acc, 0, 0, 0);
    }

    // reduce sumsq across the 4 staging threads of each row (lanes t^1, t^2 share sr)
    pa += __shfl_xor(pa, 1, 64); pa += __shfl_xor(pa, 2, 64);
    pb += __shfl_xor(pb, 1, 64); pb += __shfl_xor(pb, 2, 64);
    if (sq == 0) {
      rA[sr] = 1.0f / fmaxf(sqrtf(pa), 1e-8f);
      rB[sr] = 1.0f / fmaxf(sqrtf(pb), 1e-8f);
    }
    __syncthreads();  // rA/rB ready; all waves past their last sA/sB reads -> safe to reuse as sC

    // scale and stage C tile in LDS: C layout col=lane&31 (rj), row=(reg&3)+8*(reg>>2)+4*kh (ri)
    {
      const int rj = wj * 32 + ln;
      const float r2 = rB[rj];
#pragma unroll
      for (int reg = 0; reg < 16; ++reg) {
        const int ri = wi * 32 + (reg & 3) + 8 * (reg >> 2) + 4 * kh;
        sC[ri * CST + rj] = 1.0f - acc[reg] * rA[ri] * r2;
      }
    }
    __syncthreads();

    // diag-major coalesced stores: wave w handles rows r = w, w+4, ..., w+124 (d = d0 + r).
    // lane l holds band cell k = 2l + (d&1); LDS lane-stride 65 words -> conflict-free.
    // global addr = db[d*64 + l]: 64 consecutive floats per wave-store -> 4 cache lines.
    {
      const int d0 = i0 + j0;
      const int a65 = 65 * lane;
#pragma unroll 4
      for (int rr = 0; rr < 32; ++rr) {
        const int r = 4 * rr + w;              // 0..127
        const int d = d0 + r;                  // may be <0 or >1022 at corner tiles: fully masked
        const int pp = d & 1;
        const int roff = ((d + pp - 50) >> 1) - i0;   // ri at lane 0 (d+pp-50 is even)
        const int ri = lane + roff;
        const int rj = r - ri;
        const int kband = 2 * lane + pp;
        const int jg = j0 + rj;
        if (((unsigned)ri < 64u) & ((unsigned)rj < 64u) & (kband <= 100) &
            ((unsigned)jg < (unsigned)TT)) {
          db[(size_t)d * 64 + lane] = sC[a65 + 65 * roff + r];
        }
      }
    }
    // next tile's first K-loop __syncthreads() fences these sC reads against sA/sB overwrite
  }
}

// ---------- Kernel C: anti-diagonal DP, one wave per batch, coalesced diag reads ----------
// Band offset k = i-j+50; lane l holds cell k = 2l+p (p = d&1).
// new[k] = c + min(prev1[k-1], prev1[k+1], prev2[k])
//   p=1 (odd d): k-1 -> same lane, k+1 -> wave_shl1;  p=0: k-1 -> wave_shr1, k+1 -> same lane.
// PREFETCH DEPTH 64 (was 32): 64 in-flight rows cover ~900-cyc HBM latency (diag rows written
// early in cost_kernel are L2-evicted by its streaming), so the ~14-cyc/step dependence chain,
// not load return rate, sets the pace.
__global__ __launch_bounds__(64) void dtw_dp_kernel(const float* __restrict__ diag,
                                                    float* __restrict__ out) {
  const int b = blockIdx.x;
  const int l = threadIdx.x;
  const bool inv_odd = (l >= 50);   // k=2l+1 > 100
  const bool inv_even = (l >= 51);  // k=2l   > 100
  const float* base = diag + (size_t)b * (DROWS * 64);
  const float* pO = base + 64 + l;   // d = 1
  const float* pE = base + 128 + l;  // d = 2
  float cr[64];
#pragma unroll
  for (int t = 0; t < 32; ++t) {
    cr[2 * t] = *pO; pO += 128;      // odd d = 1,3,...,63
    cr[2 * t + 1] = *pE; pE += 128;  // even d = 2,4,...,64
  }
  float prev2 = BIGF;
  const float c00 = base[25];          // cost(0,0) lives at d=0, lane 25
  float prev1 = (l == 25) ? c00 : BIGF;
  float ans = BIGF;
  for (int itr = 0; itr < 16; ++itr) {
#pragma unroll
    for (int u = 0; u < 32; ++u) {
      // odd diagonal: d = 64*itr + 2u + 1
      const float c1 = inv_odd ? BIGF : cr[2 * u];
      cr[2 * u] = *pO; pO += 128;  // prefetch 64 diagonals ahead (read overrun stays in ws)
      const float sh = dpp_wave_shl1(prev1, BIGF);
      const float m3 = fminf(fminf(prev1, sh), prev2);
      prev2 = prev1;
      prev1 = c1 + m3;
      // even diagonal: d = 64*itr + 2u + 2
      const float c2 = inv_even ? BIGF : cr[2 * u + 1];
      cr[2 * u + 1] = *pE; pE += 128;
      const float sh2 = dpp_wave_shr1(prev1, BIGF);
      const float m32 = fminf(fminf(sh2, prev1), prev2);
      prev2 = prev1;
      prev1 = c2 + m32;
      if (itr == 15 && u == 30) ans = prev1;  // d = 1022 -> cell (511,511) at lane 25
    }
  }
  if (l == 25) out[b] = ans;
}

extern "C" void kernel_launch(void* const* d_in, const int* in_sizes, int n_in,
                              void* d_out, int out_size, void* d_ws, size_t ws_size,
                              hipStream_t stream) {
  const float* x1 = (const float*)d_in[0];
  const float* x2 = (const float*)d_in[1];
  float* out = (float*)d_out;
  float* diag = (float*)d_ws;  // 64*1088*64 floats = 17.8 MB

  cost_kernel<<<768, 256, 0, stream>>>(x1, x2, diag);
  dtw_dp_kernel<<<NB, 64, 0, stream>>>(diag, out);
}